// Round 8
// baseline (464.774 us; speedup 1.0000x reference)
//
#include <hip/hip_runtime.h>
#include <stdint.h>

// SOM BMU search: B=8192 inputs [B,256], codebook [16384,256].
// argmin_n ||x-w_n|| == argmin_n (w2[n] - 2 x.w_n)  (x2 per-row constant).
// Engine: bf16 hi/lo split GEMM on MFMA (xh.wh + xh.wl + xl.wh).
// Fast path (R8): BOTH operands in fragment-major ws layout; som_fast has
// NO LDS, NO barriers, NO explicit waitcnt -- fully independent waves at
// 4 waves/SIMD. Rounds 4-7 showed every barrier-coupled schedule pins at
// ~30% MfmaUtil with all pipes at ~30% (latency-bound, not BW-bound).

#define B_DIM 8192
#define V_DIM 256
#define N_DIM 16384

#define WS_W2_OFF     0
#define WS_PACKED_OFF 65536
#define WS_PLANES_OFF 131072
#define XPLANE_BYTES  (B_DIM * V_DIM * 2)   // 4MB
#define WPLANE_BYTES  (N_DIM * V_DIM * 2)   // 8MB
#define WS_FAST_NEED  (WS_PLANES_OFF + 2 * XPLANE_BYTES + 2 * WPLANE_BYTES)

typedef __attribute__((ext_vector_type(8))) short short8;
typedef __attribute__((ext_vector_type(4))) float f32x4;

__device__ __forceinline__ unsigned long long packKey(float s, unsigned idx) {
    unsigned u = __float_as_uint(s);
    u = (u & 0x80000000u) ? ~u : (u | 0x80000000u);
    return ((unsigned long long)u << 32) | (unsigned long long)idx;
}

__global__ __launch_bounds__(256) void w2_kernel(const float* __restrict__ W,
                                                 float* __restrict__ w2) {
    int lane = threadIdx.x & 63;
    int wv   = threadIdx.x >> 6;
    int n    = blockIdx.x * 4 + wv;
    float4 v = ((const float4*)(W + (size_t)n * V_DIM))[lane];
    float s = v.x * v.x + v.y * v.y + v.z * v.z + v.w * v.w;
    #pragma unroll
    for (int m = 32; m >= 1; m >>= 1) s += __shfl_xor(s, m);
    if (lane == 0) w2[n] = s;
}

// ---------------- fast path ----------------

__device__ __forceinline__ unsigned bfrn(float x) { // RNE f32->bf16
    unsigned u = __float_as_uint(x);
    return (u + 0x7FFFu + ((u >> 16) & 1u)) >> 16;
}
__device__ __forceinline__ float bf2f(unsigned h) { return __uint_as_float(h << 16); }

__device__ __forceinline__ void hilo8(const float4& a, const float4& b,
                                      uint4& hp, uint4& lp) {
    float v[8] = {a.x, a.y, a.z, a.w, b.x, b.y, b.z, b.w};
    unsigned hi[8], lo[8];
    #pragma unroll
    for (int i = 0; i < 8; ++i) {
        hi[i] = bfrn(v[i]);
        lo[i] = bfrn(v[i] - bf2f(hi[i]));
    }
    hp.x = hi[0] | (hi[1] << 16); hp.y = hi[2] | (hi[3] << 16);
    hp.z = hi[4] | (hi[5] << 16); hp.w = hi[6] | (hi[7] << 16);
    lp.x = lo[0] | (lo[1] << 16); lp.y = lo[2] | (lo[3] << 16);
    lp.z = lo[4] | (lo[5] << 16); lp.w = lo[6] | (lo[7] << 16);
}

// Fragment-major planes for BOTH X and W:
//   F[chunk16][ks][lane][8bf16], addr = ((chunk*8 + ks)*64 + lane)*16B
//   chunk = row/16; lane l covers row chunk*16+(l&15), k = ks*32+(l>>4)*8..+8
// == exact mfma_16x16x32_bf16 operand fragment; a wave reads 1KB contiguous.
__global__ __launch_bounds__(256) void convert_planes(const float* __restrict__ X,
                                                      const float* __restrict__ W,
                                                      unsigned short* __restrict__ Xfh,
                                                      unsigned short* __restrict__ Xfl,
                                                      unsigned short* __restrict__ Wfh,
                                                      unsigned short* __restrict__ Wfl) {
    const int gid = blockIdx.x * 256 + threadIdx.x;
    const float* src;
    unsigned short *dh, *dl;
    int tid;
    if (blockIdx.x < 1024) { // X: 512 chunks * 8 ks * 64 lanes = 262144
        tid = gid;
        const int lane = tid & 63, ck = tid >> 6;
        const int ks = ck & 7, chunk = ck >> 3;
        const int row = chunk * 16 + (lane & 15);
        const int k0  = ks * 32 + (lane >> 4) * 8;
        src = X + (size_t)row * V_DIM + k0;
        dh = Xfh; dl = Xfl;
    } else {                 // W: 1024 chunks -> 524288
        tid = gid - 262144;
        const int lane = tid & 63, ck = tid >> 6;
        const int ks = ck & 7, chunk = ck >> 3;
        const int row = chunk * 16 + (lane & 15);
        const int k0  = ks * 32 + (lane >> 4) * 8;
        src = W + (size_t)row * V_DIM + k0;
        dh = Wfh; dl = Wfl;
    }
    float4 a = ((const float4*)src)[0];
    float4 b = ((const float4*)src)[1];
    uint4 hp, lp; hilo8(a, b, hp, lp);
    *(uint4*)(dh + (size_t)tid * 8) = hp;
    *(uint4*)(dl + (size_t)tid * 8) = lp;
}

// 256 threads (4 waves 2x2, wave tile 64x64). No LDS, no barriers: waves are
// fully independent; 4 waves/SIMD (VGPR<=128) provide the latency hiding that
// barrier-coupled schedules (R4-R7, all ~30% MfmaUtil) could not.
__global__ __launch_bounds__(256, 4) void som_fast(const unsigned short* __restrict__ Xfh,
                                                   const unsigned short* __restrict__ Xfl,
                                                   const unsigned short* __restrict__ Wfh,
                                                   const unsigned short* __restrict__ Wfl,
                                                   const float* __restrict__ w2,
                                                   unsigned long long* __restrict__ packed) {
    const int t    = threadIdx.x;
    const int lane = t & 63;
    // wave-uniform ids via readfirstlane -> bases become SGPRs
    const int wvu  = __builtin_amdgcn_readfirstlane(t >> 6);
    const int wr   = wvu >> 1, wc = wvu & 1;
    const int fr   = lane & 15;
    const int kq   = lane >> 4;

    // XCD swizzle: per XCD, 32-block windows cover 4rb x 8cb (L2 locality).
    const int bid = blockIdx.x;          // 0..8191
    const int xcd = bid & 7;
    const int q   = bid >> 3;            // 0..1023
    const int w   = q >> 5;              // 0..31
    const int rb  = xcd * 8 + (w & 1) * 4 + ((q >> 3) & 3); // 0..63
    const int cb  = (w >> 1) * 8 + (q & 7);                 // 0..127
    const int r0 = rb * 128, c0 = cb * 128;

    // fragment bases (wave-uniform) + per-lane 16B offset
    const int vo = lane * 16;
    const char* Ah = (const char*)Xfh + (size_t)(rb * 8 + wr * 4) * 8192;
    const char* Al = (const char*)Xfl + (size_t)(rb * 8 + wr * 4) * 8192;
    const char* Bh = (const char*)Wfh + (size_t)(cb * 8 + wc * 4) * 8192;
    const char* Bl = (const char*)Wfl + (size_t)(cb * 8 + wc * 4) * 8192;

    f32x4 acc[4][4];
    #pragma unroll
    for (int i = 0; i < 4; ++i)
        #pragma unroll
        for (int j = 0; j < 4; ++j)
            acc[i][j] = (f32x4){0.f, 0.f, 0.f, 0.f};

    #pragma unroll
    for (int ks = 0; ks < 8; ++ks) {
        short8 fbh[4], fbl[4];
        #pragma unroll
        for (int j = 0; j < 4; ++j) {
            fbh[j] = *(const short8*)(Bh + (j * 8 + ks) * 1024 + vo);
            fbl[j] = *(const short8*)(Bl + (j * 8 + ks) * 1024 + vo);
        }
        #pragma unroll
        for (int i = 0; i < 4; ++i) {
            short8 fah = *(const short8*)(Ah + (i * 8 + ks) * 1024 + vo);
            short8 fal = *(const short8*)(Al + (i * 8 + ks) * 1024 + vo);
            __builtin_amdgcn_s_setprio(1);
            #pragma unroll
            for (int j = 0; j < 4; ++j) {
                acc[i][j] = __builtin_amdgcn_mfma_f32_16x16x32_bf16(fah, fbh[j], acc[i][j], 0, 0, 0);
                acc[i][j] = __builtin_amdgcn_mfma_f32_16x16x32_bf16(fah, fbl[j], acc[i][j], 0, 0, 0);
                acc[i][j] = __builtin_amdgcn_mfma_f32_16x16x32_bf16(fal, fbh[j], acc[i][j], 0, 0, 0);
            }
            __builtin_amdgcn_s_setprio(0);
        }
    }

    // epilogue: s = w2[n] - 2*dot; per-row min+argmin; merge via atomicMin
    float w2v[4];
    #pragma unroll
    for (int j = 0; j < 4; ++j) w2v[j] = w2[c0 + wc * 64 + j * 16 + fr];

    #pragma unroll
    for (int i = 0; i < 4; ++i) {
        #pragma unroll
        for (int r = 0; r < 4; ++r) {
            const int row = r0 + wr * 64 + i * 16 + kq * 4 + r; // C: row=(l>>4)*4+reg
            float best = 3.4e38f;
            unsigned bidx = 0u;
            #pragma unroll
            for (int j = 0; j < 4; ++j) {
                const unsigned n = (unsigned)(c0 + wc * 64 + j * 16 + fr); // C: col=l&15
                const float s = fmaf(-2.0f, acc[i][j][r], w2v[j]);
                if (s < best) { best = s; bidx = n; }
            }
            #pragma unroll
            for (int m = 1; m <= 8; m <<= 1) {
                float    ov = __shfl_xor(best, m);
                unsigned oi = (unsigned)__shfl_xor((int)bidx, m);
                if (ov < best || (ov == best && oi < bidx)) { best = ov; bidx = oi; }
            }
            if (fr == 0) atomicMin(&packed[row], packKey(best, bidx));
        }
    }
}

// ---------------- fallback path (round-2 kernel, proven) ----------------

__device__ __forceinline__ unsigned packhi2(float a, float b) {
    return (__float_as_uint(a) >> 16) | (__float_as_uint(b) & 0xFFFF0000u);
}
__device__ __forceinline__ unsigned packlo2(float a, float b) {
    float ah = __uint_as_float(__float_as_uint(a) & 0xFFFF0000u);
    float bh = __uint_as_float(__float_as_uint(b) & 0xFFFF0000u);
    return (__float_as_uint(a - ah) >> 16) | (__float_as_uint(b - bh) & 0xFFFF0000u);
}
__device__ __forceinline__ uint4 mku4(unsigned a, unsigned b, unsigned c, unsigned d) {
    uint4 r; r.x = a; r.y = b; r.z = c; r.w = d; return r;
}
__device__ __forceinline__ uint4 hi8(float4 p, float4 q) {
    return mku4(packhi2(p.x, p.y), packhi2(p.z, p.w), packhi2(q.x, q.y), packhi2(q.z, q.w));
}
__device__ __forceinline__ uint4 lo8(float4 p, float4 q) {
    return mku4(packlo2(p.x, p.y), packlo2(p.z, p.w), packlo2(q.x, q.y), packlo2(q.z, q.w));
}
__device__ __forceinline__ int lb(int row, int slot) {
    return row * 64 + ((slot ^ ((row >> 1) & 3)) << 4);
}

__global__ __launch_bounds__(256, 2) void som_mfma(const float* __restrict__ X,
                                                   const float* __restrict__ W,
                                                   const float* __restrict__ w2,
                                                   unsigned long long* __restrict__ packed) {
    __shared__ char lds[4 * 8192];
    char* Ahp = lds;
    char* Alp = lds + 8192;
    char* Bhp = lds + 16384;
    char* Blp = lds + 24576;

    const int t     = threadIdx.x;
    const int lane  = t & 63;
    const int wv    = t >> 6;
    const int wr    = wv >> 1, wc = wv & 1;
    const int fr    = lane & 15;
    const int kslot = lane >> 4;

    const int rb = blockIdx.x >> 7;
    const int cb = blockIdx.x & 127;
    const int r0 = rb * 128, c0 = cb * 128;

    const int sr = t >> 1;
    const int sh = t & 1;
    const float* xg = (const float*)X + (size_t)(r0 + sr) * V_DIM + sh * 16;
    const float* wg = (const float*)W + (size_t)(c0 + sr) * V_DIM + sh * 16;

    float4 pa[4], pb[4];
    #pragma unroll
    for (int q = 0; q < 4; ++q) { pa[q] = ((const float4*)xg)[q]; pb[q] = ((const float4*)wg)[q]; }

    f32x4 acc[4][4];
    #pragma unroll
    for (int i = 0; i < 4; ++i)
        #pragma unroll
        for (int j = 0; j < 4; ++j) acc[i][j] = (f32x4){0.f, 0.f, 0.f, 0.f};

    for (int ks = 0; ks < 8; ++ks) {
        uint4 cah0 = hi8(pa[0], pa[1]), cah1 = hi8(pa[2], pa[3]);
        uint4 cal0 = lo8(pa[0], pa[1]), cal1 = lo8(pa[2], pa[3]);
        uint4 cbh0 = hi8(pb[0], pb[1]), cbh1 = hi8(pb[2], pb[3]);
        uint4 cbl0 = lo8(pb[0], pb[1]), cbl1 = lo8(pb[2], pb[3]);

        __syncthreads();
        *(uint4*)(Ahp + lb(sr, 2 * sh))     = cah0;
        *(uint4*)(Ahp + lb(sr, 2 * sh + 1)) = cah1;
        *(uint4*)(Alp + lb(sr, 2 * sh))     = cal0;
        *(uint4*)(Alp + lb(sr, 2 * sh + 1)) = cal1;
        *(uint4*)(Bhp + lb(sr, 2 * sh))     = cbh0;
        *(uint4*)(Bhp + lb(sr, 2 * sh + 1)) = cbh1;
        *(uint4*)(Blp + lb(sr, 2 * sh))     = cbl0;
        *(uint4*)(Blp + lb(sr, 2 * sh + 1)) = cbl1;
        __syncthreads();

        if (ks + 1 < 8) {
            const float* xn = xg + (ks + 1) * 32;
            const float* wn = wg + (ks + 1) * 32;
            #pragma unroll
            for (int q = 0; q < 4; ++q) { pa[q] = ((const float4*)xn)[q]; pb[q] = ((const float4*)wn)[q]; }
        }

        short8 fah[4], fal[4], fbh[4], fbl[4];
        #pragma unroll
        for (int i = 0; i < 4; ++i) {
            int row = wr * 64 + i * 16 + fr;
            fah[i] = *(const short8*)(Ahp + lb(row, kslot));
            fal[i] = *(const short8*)(Alp + lb(row, kslot));
        }
        #pragma unroll
        for (int j = 0; j < 4; ++j) {
            int col = wc * 64 + j * 16 + fr;
            fbh[j] = *(const short8*)(Bhp + lb(col, kslot));
            fbl[j] = *(const short8*)(Blp + lb(col, kslot));
        }
        #pragma unroll
        for (int i = 0; i < 4; ++i)
            #pragma unroll
            for (int j = 0; j < 4; ++j) {
                acc[i][j] = __builtin_amdgcn_mfma_f32_16x16x32_bf16(fah[i], fbh[j], acc[i][j], 0, 0, 0);
                acc[i][j] = __builtin_amdgcn_mfma_f32_16x16x32_bf16(fah[i], fbl[j], acc[i][j], 0, 0, 0);
                acc[i][j] = __builtin_amdgcn_mfma_f32_16x16x32_bf16(fal[i], fbh[j], acc[i][j], 0, 0, 0);
            }
    }

    float w2v[4];
    #pragma unroll
    for (int j = 0; j < 4; ++j) w2v[j] = w2[c0 + wc * 64 + j * 16 + fr];

    #pragma unroll
    for (int i = 0; i < 4; ++i) {
        #pragma unroll
        for (int r = 0; r < 4; ++r) {
            const int row = r0 + wr * 64 + i * 16 + kslot * 4 + r;
            float best = 3.4e38f;
            unsigned bidx = 0u;
            #pragma unroll
            for (int j = 0; j < 4; ++j) {
                const unsigned n = (unsigned)(c0 + wc * 64 + j * 16 + fr);
                const float s = fmaf(-2.0f, acc[i][j][r], w2v[j]);
                if (s < best) { best = s; bidx = n; }
            }
            #pragma unroll
            for (int m = 1; m <= 8; m <<= 1) {
                float    ov = __shfl_xor(best, m);
                unsigned oi = (unsigned)__shfl_xor((int)bidx, m);
                if (ov < best || (ov == best && oi < bidx)) { best = ov; bidx = oi; }
            }
            if (fr == 0) atomicMin(&packed[row], packKey(best, bidx));
        }
    }
}

__global__ __launch_bounds__(256) void finalize(const float* __restrict__ X,
                                                const float* __restrict__ loc,
                                                const unsigned long long* __restrict__ packed,
                                                float* __restrict__ out) {
    int lane = threadIdx.x & 63;
    int wv   = threadIdx.x >> 6;
    int b    = blockIdx.x * 4 + wv;
    float4 v = ((const float4*)(X + (size_t)b * V_DIM))[lane];
    float x2 = v.x * v.x + v.y * v.y + v.z * v.z + v.w * v.w;
    #pragma unroll
    for (int m = 32; m >= 1; m >>= 1) x2 += __shfl_xor(x2, m);
    if (lane == 0) {
        unsigned long long p = packed[b];
        unsigned key = (unsigned)(p >> 32);
        unsigned idx = (unsigned)(p & 0xFFFFFFFFu);
        unsigned sb  = (key & 0x80000000u) ? (key & 0x7FFFFFFFu) : ~key;
        float s  = __uint_as_float(sb);
        float d2 = fmaxf(x2 + s, 0.0f);
        out[2 * b]     = loc[2 * idx];
        out[2 * b + 1] = loc[2 * idx + 1];
        out[2 * B_DIM + b] = sqrtf(d2);
    }
}

extern "C" void kernel_launch(void* const* d_in, const int* in_sizes, int n_in,
                              void* d_out, int out_size, void* d_ws, size_t ws_size,
                              hipStream_t stream) {
    const float* X = (const float*)d_in[0];   // [8192,256]
    const float* W = (const float*)d_in[1];   // [16384,256]
    const float* L = (const float*)d_in[2];   // [16384,2]
    float* out = (float*)d_out;

    float* w2 = (float*)((char*)d_ws + WS_W2_OFF);
    unsigned long long* packed = (unsigned long long*)((char*)d_ws + WS_PACKED_OFF);

    hipMemsetAsync(packed, 0xFF, B_DIM * sizeof(unsigned long long), stream);
    w2_kernel<<<N_DIM / 4, 256, 0, stream>>>(W, w2);

    if (ws_size >= (size_t)WS_FAST_NEED) {
        unsigned short* Xfh = (unsigned short*)((char*)d_ws + WS_PLANES_OFF);
        unsigned short* Xfl = (unsigned short*)((char*)Xfh + XPLANE_BYTES);
        unsigned short* Wfh = (unsigned short*)((char*)Xfl + XPLANE_BYTES);
        unsigned short* Wfl = (unsigned short*)((char*)Wfh + WPLANE_BYTES);
        convert_planes<<<3072, 256, 0, stream>>>(X, W, Xfh, Xfl, Wfh, Wfl);
        som_fast<<<(B_DIM / 128) * (N_DIM / 128), 256, 0, stream>>>(Xfh, Xfl, Wfh, Wfl, w2, packed);
    } else {
        som_mfma<<<(B_DIM / 128) * (N_DIM / 128), 256, 0, stream>>>(X, W, w2, packed);
    }
    finalize<<<B_DIM / 4, 256, 0, stream>>>(X, L, packed, out);
}

// Round 9
// 271.821 us; speedup vs baseline: 1.7099x; 1.7099x over previous
//
#include <hip/hip_runtime.h>
#include <stdint.h>

// SOM BMU search: B=8192 inputs [B,256], codebook [16384,256].
// argmin_n ||x-w_n|| == argmin_n (w2[n] - 2 x.w_n)  (x2 per-row constant).
// Engine: bf16 hi/lo split GEMM on MFMA (xh.wh + xh.wl + xl.wh).
// R9: R6 structure (128x128, 4-plane gl16 LDS, dbuf, 2 blocks/CU) with
// TERM-MAJOR MFMA ordering: 16 independent MFMAs per sweep instead of
// 3 dependent MFMAs per accumulator (in-order issue stalled on acc
// latency -> the 27-30% MfmaUtil invariant of R2-R7).

#define B_DIM 8192
#define V_DIM 256
#define N_DIM 16384

#define WS_W2_OFF     0
#define WS_PACKED_OFF 65536
#define WS_PLANES_OFF 131072
#define XPLANE_BYTES  (B_DIM * V_DIM * 2)   // 4MB
#define WPLANE_BYTES  (N_DIM * V_DIM * 2)   // 8MB
#define WS_FAST_NEED  (WS_PLANES_OFF + 2 * XPLANE_BYTES + 2 * WPLANE_BYTES)

typedef __attribute__((ext_vector_type(8))) short short8;
typedef __attribute__((ext_vector_type(4))) float f32x4;

__device__ __forceinline__ unsigned long long packKey(float s, unsigned idx) {
    unsigned u = __float_as_uint(s);
    u = (u & 0x80000000u) ? ~u : (u | 0x80000000u);
    return ((unsigned long long)u << 32) | (unsigned long long)idx;
}

__global__ __launch_bounds__(256) void w2_kernel(const float* __restrict__ W,
                                                 float* __restrict__ w2) {
    int lane = threadIdx.x & 63;
    int wv   = threadIdx.x >> 6;
    int n    = blockIdx.x * 4 + wv;
    float4 v = ((const float4*)(W + (size_t)n * V_DIM))[lane];
    float s = v.x * v.x + v.y * v.y + v.z * v.z + v.w * v.w;
    #pragma unroll
    for (int m = 32; m >= 1; m >>= 1) s += __shfl_xor(s, m);
    if (lane == 0) w2[n] = s;
}

// ---------------- fast path ----------------

__device__ __forceinline__ unsigned bfrn(float x) { // RNE f32->bf16
    unsigned u = __float_as_uint(x);
    return (u + 0x7FFFu + ((u >> 16) & 1u)) >> 16;
}
__device__ __forceinline__ float bf2f(unsigned h) { return __uint_as_float(h << 16); }

// Convert X,W into hi/lo bf16 planes, pre-swizzled: within each 64B k-window
// (4 slots of 16B), slot s stored at s ^ ((row>>1)&3) -- the LDS image the
// linear global_load_lds staging expects; ds_read applies the same XOR.
__global__ __launch_bounds__(256) void convert_planes(const float* __restrict__ X,
                                                      const float* __restrict__ W,
                                                      unsigned short* __restrict__ Xh,
                                                      unsigned short* __restrict__ Xl,
                                                      unsigned short* __restrict__ Wh,
                                                      unsigned short* __restrict__ Wl) {
    int gid = blockIdx.x * 256 + threadIdx.x;
    int s   = gid & 31;        // 16B slot within 512B row (8 floats)
    int row = gid >> 5;
    const float* src;
    unsigned short *dh, *dl;
    int r;
    if (row < B_DIM) { r = row; src = X + (size_t)r * V_DIM; dh = Xh; dl = Xl; }
    else             { r = row - B_DIM; src = W + (size_t)r * V_DIM; dh = Wh; dl = Wl; }

    float4 a = ((const float4*)src)[s * 2];
    float4 b = ((const float4*)src)[s * 2 + 1];
    float v[8] = {a.x, a.y, a.z, a.w, b.x, b.y, b.z, b.w};
    unsigned hi[8], lo[8];
    #pragma unroll
    for (int i = 0; i < 8; ++i) {
        hi[i] = bfrn(v[i]);
        lo[i] = bfrn(v[i] - bf2f(hi[i]));
    }
    uint4 hp, lp;
    hp.x = hi[0] | (hi[1] << 16); hp.y = hi[2] | (hi[3] << 16);
    hp.z = hi[4] | (hi[5] << 16); hp.w = hi[6] | (hi[7] << 16);
    lp.x = lo[0] | (lo[1] << 16); lp.y = lo[2] | (lo[3] << 16);
    lp.z = lo[4] | (lo[5] << 16); lp.w = lo[6] | (lo[7] << 16);

    int sp = (s & ~3) | ((s & 3) ^ ((r >> 1) & 3)); // pre-swizzle
    *(uint4*)(dh + (size_t)r * V_DIM + sp * 8) = hp;
    *(uint4*)(dl + (size_t)r * V_DIM + sp * 8) = lp;
}

__device__ __forceinline__ void gl16(const void* g, void* l) {
    __builtin_amdgcn_global_load_lds((const __attribute__((address_space(1))) unsigned int*)g,
                                     (__attribute__((address_space(3))) unsigned int*)l,
                                     16, 0, 0);
}

#define BARX()   asm volatile("s_barrier" ::: "memory")
#define VMC8()   asm volatile("s_waitcnt vmcnt(8)" ::: "memory")
#define VMC0()   asm volatile("s_waitcnt vmcnt(0)" ::: "memory")

// 256 threads (4 waves, 2x2), wave tile 64x64, dbuf LDS 64KB -> 2 blocks/CU.
__global__ __launch_bounds__(256, 2) void som_fast(const unsigned short* __restrict__ Xh,
                                                   const unsigned short* __restrict__ Xl,
                                                   const unsigned short* __restrict__ Wh,
                                                   const unsigned short* __restrict__ Wl,
                                                   const float* __restrict__ w2,
                                                   unsigned long long* __restrict__ packed) {
    // buffer b at +b*32768; planes: Ah@0 Al@8K Bh@16K Bl@24K; plane=[128rows][64B]
    __shared__ __align__(16) char lds[65536];

    const int t    = threadIdx.x; // 0..255
    const int lane = t & 63;
    const int wv   = t >> 6;      // 0..3
    const int wr   = wv >> 1, wc = wv & 1; // wave quadrant (64x64)
    const int fr   = lane & 15;
    const int kq   = lane >> 4;

    // Swizzle: XCD bid&7; within XCD, 32-block windows cover 4rb x 8cb
    // (X 0.5MB + W 1MB < 4MB L2).
    const int bid = blockIdx.x;          // 0..8191
    const int xcd = bid & 7;
    const int q   = bid >> 3;            // 0..1023
    const int w   = q >> 5;              // 0..31
    const int rb  = xcd * 8 + (w & 1) * 4 + ((q >> 3) & 3); // 0..63
    const int cb  = (w >> 1) * 8 + (q & 7);                 // 0..127
    const int r0 = rb * 128, c0 = cb * 128;

    // staging: thread covers (row = t>>2 [+64], slot = t&3); ws pre-swizzled.
    const char* pXh = (const char*)Xh + (((size_t)(r0 + (t >> 2))) << 9) + ((t & 3) << 4);
    const char* pXl = (const char*)Xl + (((size_t)(r0 + (t >> 2))) << 9) + ((t & 3) << 4);
    const char* pWh = (const char*)Wh + (((size_t)(c0 + (t >> 2))) << 9) + ((t & 3) << 4);
    const char* pWl = (const char*)Wl + (((size_t)(c0 + (t >> 2))) << 9) + ((t & 3) << 4);
    const int t16 = t * 16;

    // 8 gl16 per thread per K-tile; rows +64 are global +32768 (64*512B)
#define ISSUE(kk, B)                                            \
    do {                                                        \
        gl16(pXh + (kk) * 64,         (B) + t16);               \
        gl16(pXh + 32768 + (kk) * 64, (B) + 4096  + t16);       \
        gl16(pXl + (kk) * 64,         (B) + 8192  + t16);       \
        gl16(pXl + 32768 + (kk) * 64, (B) + 12288 + t16);       \
        gl16(pWh + (kk) * 64,         (B) + 16384 + t16);       \
        gl16(pWh + 32768 + (kk) * 64, (B) + 20480 + t16);       \
        gl16(pWl + (kk) * 64,         (B) + 24576 + t16);       \
        gl16(pWl + 32768 + (kk) * 64, (B) + 28672 + t16);       \
    } while (0)

    f32x4 acc[4][4];
    #pragma unroll
    for (int i = 0; i < 4; ++i)
        #pragma unroll
        for (int j = 0; j < 4; ++j)
            acc[i][j] = (f32x4){0.f, 0.f, 0.f, 0.f};

    char* buf0 = lds;
    char* buf1 = lds + 32768;

    ISSUE(0, buf0); // prologue: tile 0 in flight

    // Per tile: barA (prev reads done everywhere; nxt reusable) -> issue ks+1
    // -> vmcnt(8) (tile ks landed; ks+1 stays in flight) -> barB -> compute.
    #pragma unroll
    for (int ks = 0; ks < 8; ++ks) {
        char* cur = (ks & 1) ? buf1 : buf0;
        char* nxt = (ks & 1) ? buf0 : buf1;

        BARX(); // barA
        if (ks < 7) { ISSUE(ks + 1, nxt); VMC8(); }
        else        { VMC0(); }
        BARX(); // barB: tile ks resident for all waves

        short8 fah[4], fal[4], fbh[4], fbl[4];
        #pragma unroll
        for (int j = 0; j < 4; ++j) {
            const int col = wc * 64 + j * 16 + fr;
            const int off = col * 64 + ((kq ^ ((col >> 1) & 3)) << 4);
            fbh[j] = *(const short8*)(cur + 16384 + off);
            fbl[j] = *(const short8*)(cur + 24576 + off);
        }
        #pragma unroll
        for (int i = 0; i < 4; ++i) {
            const int row = wr * 64 + i * 16 + fr;
            const int off = row * 64 + ((kq ^ ((row >> 1) & 3)) << 4);
            fah[i] = *(const short8*)(cur + off);
            fal[i] = *(const short8*)(cur + 8192 + off);
        }

        // TERM-MAJOR sweeps: every consecutive MFMA writes a DIFFERENT
        // accumulator (15 independent ops between reuses of acc[i][j]),
        // so in-order issue never stalls on MFMA result latency.
        // Per-acc addition order (hh, then hl, then lh) is unchanged ->
        // bitwise-identical accumulation.
        __builtin_amdgcn_s_setprio(1);
        #pragma unroll
        for (int i = 0; i < 4; ++i)
            #pragma unroll
            for (int j = 0; j < 4; ++j)
                acc[i][j] = __builtin_amdgcn_mfma_f32_16x16x32_bf16(fah[i], fbh[j], acc[i][j], 0, 0, 0);
        #pragma unroll
        for (int i = 0; i < 4; ++i)
            #pragma unroll
            for (int j = 0; j < 4; ++j)
                acc[i][j] = __builtin_amdgcn_mfma_f32_16x16x32_bf16(fah[i], fbl[j], acc[i][j], 0, 0, 0);
        #pragma unroll
        for (int i = 0; i < 4; ++i)
            #pragma unroll
            for (int j = 0; j < 4; ++j)
                acc[i][j] = __builtin_amdgcn_mfma_f32_16x16x32_bf16(fal[i], fbh[j], acc[i][j], 0, 0, 0);
        __builtin_amdgcn_s_setprio(0);
    }
#undef ISSUE

    // epilogue: s = w2[n] - 2*dot; per-row min+argmin; merge via atomicMin
    float w2v[4];
    #pragma unroll
    for (int j = 0; j < 4; ++j) w2v[j] = w2[c0 + wc * 64 + j * 16 + fr];

    #pragma unroll
    for (int i = 0; i < 4; ++i) {
        #pragma unroll
        for (int r = 0; r < 4; ++r) {
            const int row = r0 + wr * 64 + i * 16 + kq * 4 + r; // C: row=(l>>4)*4+reg
            float best = 3.4e38f;
            unsigned bidx = 0u;
            #pragma unroll
            for (int j = 0; j < 4; ++j) {
                const unsigned n = (unsigned)(c0 + wc * 64 + j * 16 + fr); // C: col=l&15
                const float s = fmaf(-2.0f, acc[i][j][r], w2v[j]);
                if (s < best) { best = s; bidx = n; }
            }
            #pragma unroll
            for (int m = 1; m <= 8; m <<= 1) { // reduce across 16 fr-lanes
                float    ov = __shfl_xor(best, m);
                unsigned oi = (unsigned)__shfl_xor((int)bidx, m);
                if (ov < best || (ov == best && oi < bidx)) { best = ov; bidx = oi; }
            }
            if (fr == 0) atomicMin(&packed[row], packKey(best, bidx));
        }
    }
}

// ---------------- fallback path (round-2 kernel, proven) ----------------

__device__ __forceinline__ unsigned packhi2(float a, float b) {
    return (__float_as_uint(a) >> 16) | (__float_as_uint(b) & 0xFFFF0000u);
}
__device__ __forceinline__ unsigned packlo2(float a, float b) {
    float ah = __uint_as_float(__float_as_uint(a) & 0xFFFF0000u);
    float bh = __uint_as_float(__float_as_uint(b) & 0xFFFF0000u);
    return (__float_as_uint(a - ah) >> 16) | (__float_as_uint(b - bh) & 0xFFFF0000u);
}
__device__ __forceinline__ uint4 mku4(unsigned a, unsigned b, unsigned c, unsigned d) {
    uint4 r; r.x = a; r.y = b; r.z = c; r.w = d; return r;
}
__device__ __forceinline__ uint4 hi8(float4 p, float4 q) {
    return mku4(packhi2(p.x, p.y), packhi2(p.z, p.w), packhi2(q.x, q.y), packhi2(q.z, q.w));
}
__device__ __forceinline__ uint4 lo8(float4 p, float4 q) {
    return mku4(packlo2(p.x, p.y), packlo2(p.z, p.w), packlo2(q.x, q.y), packlo2(q.z, q.w));
}
__device__ __forceinline__ int lb(int row, int slot) {
    return row * 64 + ((slot ^ ((row >> 1) & 3)) << 4);
}

__global__ __launch_bounds__(256, 2) void som_mfma(const float* __restrict__ X,
                                                   const float* __restrict__ W,
                                                   const float* __restrict__ w2,
                                                   unsigned long long* __restrict__ packed) {
    __shared__ char lds[4 * 8192];
    char* Ahp = lds;
    char* Alp = lds + 8192;
    char* Bhp = lds + 16384;
    char* Blp = lds + 24576;

    const int t     = threadIdx.x;
    const int lane  = t & 63;
    const int wv    = t >> 6;
    const int wr    = wv >> 1, wc = wv & 1;
    const int fr    = lane & 15;
    const int kslot = lane >> 4;

    const int rb = blockIdx.x >> 7;
    const int cb = blockIdx.x & 127;
    const int r0 = rb * 128, c0 = cb * 128;

    const int sr = t >> 1;
    const int sh = t & 1;
    const float* xg = (const float*)X + (size_t)(r0 + sr) * V_DIM + sh * 16;
    const float* wg = (const float*)W + (size_t)(c0 + sr) * V_DIM + sh * 16;

    float4 pa[4], pb[4];
    #pragma unroll
    for (int q = 0; q < 4; ++q) { pa[q] = ((const float4*)xg)[q]; pb[q] = ((const float4*)wg)[q]; }

    f32x4 acc[4][4];
    #pragma unroll
    for (int i = 0; i < 4; ++i)
        #pragma unroll
        for (int j = 0; j < 4; ++j) acc[i][j] = (f32x4){0.f, 0.f, 0.f, 0.f};

    for (int ks = 0; ks < 8; ++ks) {
        uint4 cah0 = hi8(pa[0], pa[1]), cah1 = hi8(pa[2], pa[3]);
        uint4 cal0 = lo8(pa[0], pa[1]), cal1 = lo8(pa[2], pa[3]);
        uint4 cbh0 = hi8(pb[0], pb[1]), cbh1 = hi8(pb[2], pb[3]);
        uint4 cbl0 = lo8(pb[0], pb[1]), cbl1 = lo8(pb[2], pb[3]);

        __syncthreads();
        *(uint4*)(Ahp + lb(sr, 2 * sh))     = cah0;
        *(uint4*)(Ahp + lb(sr, 2 * sh + 1)) = cah1;
        *(uint4*)(Alp + lb(sr, 2 * sh))     = cal0;
        *(uint4*)(Alp + lb(sr, 2 * sh + 1)) = cal1;
        *(uint4*)(Bhp + lb(sr, 2 * sh))     = cbh0;
        *(uint4*)(Bhp + lb(sr, 2 * sh + 1)) = cbh1;
        *(uint4*)(Blp + lb(sr, 2 * sh))     = cbl0;
        *(uint4*)(Blp + lb(sr, 2 * sh + 1)) = cbl1;
        __syncthreads();

        if (ks + 1 < 8) {
            const float* xn = xg + (ks + 1) * 32;
            const float* wn = wg + (ks + 1) * 32;
            #pragma unroll
            for (int q = 0; q < 4; ++q) { pa[q] = ((const float4*)xn)[q]; pb[q] = ((const float4*)wn)[q]; }
        }

        short8 fah[4], fal[4], fbh[4], fbl[4];
        #pragma unroll
        for (int i = 0; i < 4; ++i) {
            int row = wr * 64 + i * 16 + fr;
            fah[i] = *(const short8*)(Ahp + lb(row, kslot));
            fal[i] = *(const short8*)(Alp + lb(row, kslot));
        }
        #pragma unroll
        for (int j = 0; j < 4; ++j) {
            int col = wc * 64 + j * 16 + fr;
            fbh[j] = *(const short8*)(Bhp + lb(col, kslot));
            fbl[j] = *(const short8*)(Blp + lb(col, kslot));
        }
        #pragma unroll
        for (int i = 0; i < 4; ++i)
            #pragma unroll
            for (int j = 0; j < 4; ++j) {
                acc[i][j] = __builtin_amdgcn_mfma_f32_16x16x32_bf16(fah[i], fbh[j], acc[i][j], 0, 0, 0);
                acc[i][j] = __builtin_amdgcn_mfma_f32_16x16x32_bf16(fah[i], fbl[j], acc[i][j], 0, 0, 0);
                acc[i][j] = __builtin_amdgcn_mfma_f32_16x16x32_bf16(fal[i], fbh[j], acc[i][j], 0, 0, 0);
            }
    }

    float w2v[4];
    #pragma unroll
    for (int j = 0; j < 4; ++j) w2v[j] = w2[c0 + wc * 64 + j * 16 + fr];

    #pragma unroll
    for (int i = 0; i < 4; ++i) {
        #pragma unroll
        for (int r = 0; r < 4; ++r) {
            const int row = r0 + wr * 64 + i * 16 + kslot * 4 + r;
            float best = 3.4e38f;
            unsigned bidx = 0u;
            #pragma unroll
            for (int j = 0; j < 4; ++j) {
                const unsigned n = (unsigned)(c0 + wc * 64 + j * 16 + fr);
                const float s = fmaf(-2.0f, acc[i][j][r], w2v[j]);
                if (s < best) { best = s; bidx = n; }
            }
            #pragma unroll
            for (int m = 1; m <= 8; m <<= 1) {
                float    ov = __shfl_xor(best, m);
                unsigned oi = (unsigned)__shfl_xor((int)bidx, m);
                if (ov < best || (ov == best && oi < bidx)) { best = ov; bidx = oi; }
            }
            if (fr == 0) atomicMin(&packed[row], packKey(best, bidx));
        }
    }
}

__global__ __launch_bounds__(256) void finalize(const float* __restrict__ X,
                                                const float* __restrict__ loc,
                                                const unsigned long long* __restrict__ packed,
                                                float* __restrict__ out) {
    int lane = threadIdx.x & 63;
    int wv   = threadIdx.x >> 6;
    int b    = blockIdx.x * 4 + wv;
    float4 v = ((const float4*)(X + (size_t)b * V_DIM))[lane];
    float x2 = v.x * v.x + v.y * v.y + v.z * v.z + v.w * v.w;
    #pragma unroll
    for (int m = 32; m >= 1; m >>= 1) x2 += __shfl_xor(x2, m);
    if (lane == 0) {
        unsigned long long p = packed[b];
        unsigned key = (unsigned)(p >> 32);
        unsigned idx = (unsigned)(p & 0xFFFFFFFFu);
        unsigned sb  = (key & 0x80000000u) ? (key & 0x7FFFFFFFu) : ~key;
        float s  = __uint_as_float(sb);
        float d2 = fmaxf(x2 + s, 0.0f);
        out[2 * b]     = loc[2 * idx];
        out[2 * b + 1] = loc[2 * idx + 1];
        out[2 * B_DIM + b] = sqrtf(d2);
    }
}

extern "C" void kernel_launch(void* const* d_in, const int* in_sizes, int n_in,
                              void* d_out, int out_size, void* d_ws, size_t ws_size,
                              hipStream_t stream) {
    const float* X = (const float*)d_in[0];   // [8192,256]
    const float* W = (const float*)d_in[1];   // [16384,256]
    const float* L = (const float*)d_in[2];   // [16384,2]
    float* out = (float*)d_out;

    float* w2 = (float*)((char*)d_ws + WS_W2_OFF);
    unsigned long long* packed = (unsigned long long*)((char*)d_ws + WS_PACKED_OFF);

    hipMemsetAsync(packed, 0xFF, B_DIM * sizeof(unsigned long long), stream);
    w2_kernel<<<N_DIM / 4, 256, 0, stream>>>(W, w2);

    if (ws_size >= (size_t)WS_FAST_NEED) {
        unsigned short* Xh = (unsigned short*)((char*)d_ws + WS_PLANES_OFF);
        unsigned short* Xl = (unsigned short*)((char*)Xh + XPLANE_BYTES);
        unsigned short* Wh = (unsigned short*)((char*)Xl + XPLANE_BYTES);
        unsigned short* Wl = (unsigned short*)((char*)Wh + WPLANE_BYTES);
        convert_planes<<<(B_DIM + N_DIM) * 32 / 256, 256, 0, stream>>>(X, W, Xh, Xl, Wh, Wl);
        som_fast<<<(B_DIM / 128) * (N_DIM / 128), 256, 0, stream>>>(Xh, Xl, Wh, Wl, w2, packed);
    } else {
        som_mfma<<<(B_DIM / 128) * (N_DIM / 128), 256, 0, stream>>>(X, W, w2, packed);
    }
    finalize<<<B_DIM / 4, 256, 0, stream>>>(X, L, packed, out);
}

// Round 10
// 254.511 us; speedup vs baseline: 1.8261x; 1.0680x over previous
//
#include <hip/hip_runtime.h>
#include <stdint.h>

// SOM BMU search: B=8192 inputs [B,256], codebook [16384,256].
// argmin_n ||x-w_n|| == argmin_n (w2[n] - 2 x.w_n)  (x2 per-row constant).
// Engine: bf16 hi/lo split GEMM on MFMA (xh.wh + xh.wl + xl.wh).
// R10: zero-barrier all-register pipeline. Both operands fragment-major in
// d_ws (R8 layout, proven bitwise-correct); per-wave register double-buffer;
// no LDS, no barriers -> no in-phase read/MFMA serialization (the R2-R9
// 27-30% MfmaUtil invariant). R8's failures fixed: (256,2) -> no spill;
// ~210 VGPR -> 2 blocks/CU -> per-XCD L2 working set fits (no thrash).

#define B_DIM 8192
#define V_DIM 256
#define N_DIM 16384

#define WS_W2_OFF     0
#define WS_PACKED_OFF 65536
#define WS_PLANES_OFF 131072
#define XPLANE_BYTES  (B_DIM * V_DIM * 2)   // 4MB
#define WPLANE_BYTES  (N_DIM * V_DIM * 2)   // 8MB
#define WS_FAST_NEED  (WS_PLANES_OFF + 2 * XPLANE_BYTES + 2 * WPLANE_BYTES)

typedef __attribute__((ext_vector_type(8))) short short8;
typedef __attribute__((ext_vector_type(4))) float f32x4;

__device__ __forceinline__ unsigned long long packKey(float s, unsigned idx) {
    unsigned u = __float_as_uint(s);
    u = (u & 0x80000000u) ? ~u : (u | 0x80000000u);
    return ((unsigned long long)u << 32) | (unsigned long long)idx;
}

__global__ __launch_bounds__(256) void w2_kernel(const float* __restrict__ W,
                                                 float* __restrict__ w2) {
    int lane = threadIdx.x & 63;
    int wv   = threadIdx.x >> 6;
    int n    = blockIdx.x * 4 + wv;
    float4 v = ((const float4*)(W + (size_t)n * V_DIM))[lane];
    float s = v.x * v.x + v.y * v.y + v.z * v.z + v.w * v.w;
    #pragma unroll
    for (int m = 32; m >= 1; m >>= 1) s += __shfl_xor(s, m);
    if (lane == 0) w2[n] = s;
}

// ---------------- fast path ----------------

__device__ __forceinline__ unsigned bfrn(float x) { // RNE f32->bf16
    unsigned u = __float_as_uint(x);
    return (u + 0x7FFFu + ((u >> 16) & 1u)) >> 16;
}
__device__ __forceinline__ float bf2f(unsigned h) { return __uint_as_float(h << 16); }

__device__ __forceinline__ void hilo8(const float4& a, const float4& b,
                                      uint4& hp, uint4& lp) {
    float v[8] = {a.x, a.y, a.z, a.w, b.x, b.y, b.z, b.w};
    unsigned hi[8], lo[8];
    #pragma unroll
    for (int i = 0; i < 8; ++i) {
        hi[i] = bfrn(v[i]);
        lo[i] = bfrn(v[i] - bf2f(hi[i]));
    }
    hp.x = hi[0] | (hi[1] << 16); hp.y = hi[2] | (hi[3] << 16);
    hp.z = hi[4] | (hi[5] << 16); hp.w = hi[6] | (hi[7] << 16);
    lp.x = lo[0] | (lo[1] << 16); lp.y = lo[2] | (lo[3] << 16);
    lp.z = lo[4] | (lo[5] << 16); lp.w = lo[6] | (lo[7] << 16);
}

// Fragment-major planes for BOTH X and W (R8 layout, proven):
//   F[chunk16][ks][lane][8bf16], addr = ((chunk*8 + ks)*64 + lane)*16B
//   chunk = row/16; lane l covers row chunk*16+(l&15), k = ks*32+(l>>4)*8..+8
// == exact mfma_16x16x32_bf16 operand fragment; a wave reads 1KB contiguous.
__global__ __launch_bounds__(256) void convert_planes(const float* __restrict__ X,
                                                      const float* __restrict__ W,
                                                      unsigned short* __restrict__ Xfh,
                                                      unsigned short* __restrict__ Xfl,
                                                      unsigned short* __restrict__ Wfh,
                                                      unsigned short* __restrict__ Wfl) {
    const int gid = blockIdx.x * 256 + threadIdx.x;
    const float* src;
    unsigned short *dh, *dl;
    int tid;
    if (blockIdx.x < 1024) { // X: 512 chunks * 8 ks * 64 lanes = 262144
        tid = gid;
        const int lane = tid & 63, ck = tid >> 6;
        const int ks = ck & 7, chunk = ck >> 3;
        const int row = chunk * 16 + (lane & 15);
        const int k0  = ks * 32 + (lane >> 4) * 8;
        src = X + (size_t)row * V_DIM + k0;
        dh = Xfh; dl = Xfl;
    } else {                 // W: 1024 chunks -> 524288
        tid = gid - 262144;
        const int lane = tid & 63, ck = tid >> 6;
        const int ks = ck & 7, chunk = ck >> 3;
        const int row = chunk * 16 + (lane & 15);
        const int k0  = ks * 32 + (lane >> 4) * 8;
        src = W + (size_t)row * V_DIM + k0;
        dh = Wfh; dl = Wfl;
    }
    float4 a = ((const float4*)src)[0];
    float4 b = ((const float4*)src)[1];
    uint4 hp, lp; hilo8(a, b, hp, lp);
    *(uint4*)(dh + (size_t)tid * 8) = hp;
    *(uint4*)(dl + (size_t)tid * 8) = lp;
}

// 256 threads (4 waves 2x2, wave tile 64x64). No LDS, no barriers. Each wave
// runs its own register-double-buffered pipeline: issue tile ks+1's 16
// fragment loads, then 48 MFMAs on tile ks (loads hide under ~900 cyc MFMA).
// ~210 VGPR -> 2 waves/SIMD -> 2 blocks/CU (keeps R6's proven L2 regime).
__global__ __launch_bounds__(256, 2) void som_fast(const unsigned short* __restrict__ Xfh,
                                                   const unsigned short* __restrict__ Xfl,
                                                   const unsigned short* __restrict__ Wfh,
                                                   const unsigned short* __restrict__ Wfl,
                                                   const float* __restrict__ w2,
                                                   unsigned long long* __restrict__ packed) {
    const int t    = threadIdx.x;
    const int lane = t & 63;
    const int wvu  = __builtin_amdgcn_readfirstlane(t >> 6); // SGPR wave id
    const int wr   = wvu >> 1, wc = wvu & 1;
    const int fr   = lane & 15;
    const int kq   = lane >> 4;

    // XCD swizzle: per XCD, 32-block windows cover 4rb x 8cb (L2 locality).
    const int bid = blockIdx.x;          // 0..8191
    const int xcd = bid & 7;
    const int q   = bid >> 3;            // 0..1023
    const int w   = q >> 5;              // 0..31
    const int rb  = xcd * 8 + (w & 1) * 4 + ((q >> 3) & 3); // 0..63
    const int cb  = (w >> 1) * 8 + (q & 7);                 // 0..127
    const int r0 = rb * 128, c0 = cb * 128;

    // fragment bases (wave-uniform) + per-lane 16B offset
    const int vo = lane * 16;
    const char* Ah = (const char*)Xfh + (size_t)(rb * 8 + wr * 4) * 8192;
    const char* Al = (const char*)Xfl + (size_t)(rb * 8 + wr * 4) * 8192;
    const char* Bh = (const char*)Wfh + (size_t)(cb * 8 + wc * 4) * 8192;
    const char* Bl = (const char*)Wfl + (size_t)(cb * 8 + wc * 4) * 8192;

    f32x4 acc[4][4];
    #pragma unroll
    for (int i = 0; i < 4; ++i)
        #pragma unroll
        for (int j = 0; j < 4; ++j)
            acc[i][j] = (f32x4){0.f, 0.f, 0.f, 0.f};

    // register double-buffer: [buf][plane][i] -- all indices static after unroll
    short8 fa[2][2][4], fb[2][2][4];

#define LOADT(buf, kk)                                                      \
    do {                                                                    \
        _Pragma("unroll")                                                   \
        for (int i = 0; i < 4; ++i) {                                       \
            fa[buf][0][i] = *(const short8*)(Ah + (i * 8 + (kk)) * 1024 + vo); \
            fa[buf][1][i] = *(const short8*)(Al + (i * 8 + (kk)) * 1024 + vo); \
            fb[buf][0][i] = *(const short8*)(Bh + (i * 8 + (kk)) * 1024 + vo); \
            fb[buf][1][i] = *(const short8*)(Bl + (i * 8 + (kk)) * 1024 + vo); \
        }                                                                   \
    } while (0)

    LOADT(0, 0);

    #pragma unroll
    for (int ks = 0; ks < 8; ++ks) {
        const int cur = ks & 1;
        const int nxt = cur ^ 1;
        if (ks < 7) LOADT(nxt, ks + 1);   // issue-early; flies under MFMAs

        __builtin_amdgcn_s_setprio(1);
        #pragma unroll
        for (int i = 0; i < 4; ++i)
            #pragma unroll
            for (int j = 0; j < 4; ++j) {
                acc[i][j] = __builtin_amdgcn_mfma_f32_16x16x32_bf16(fa[cur][0][i], fb[cur][0][j], acc[i][j], 0, 0, 0);
                acc[i][j] = __builtin_amdgcn_mfma_f32_16x16x32_bf16(fa[cur][0][i], fb[cur][1][j], acc[i][j], 0, 0, 0);
                acc[i][j] = __builtin_amdgcn_mfma_f32_16x16x32_bf16(fa[cur][1][i], fb[cur][0][j], acc[i][j], 0, 0, 0);
            }
        __builtin_amdgcn_s_setprio(0);
    }
#undef LOADT

    // epilogue: s = w2[n] - 2*dot; per-row min+argmin; merge via atomicMin
    float w2v[4];
    #pragma unroll
    for (int j = 0; j < 4; ++j) w2v[j] = w2[c0 + wc * 64 + j * 16 + fr];

    #pragma unroll
    for (int i = 0; i < 4; ++i) {
        #pragma unroll
        for (int r = 0; r < 4; ++r) {
            const int row = r0 + wr * 64 + i * 16 + kq * 4 + r; // C: row=(l>>4)*4+reg
            float best = 3.4e38f;
            unsigned bidx = 0u;
            #pragma unroll
            for (int j = 0; j < 4; ++j) {
                const unsigned n = (unsigned)(c0 + wc * 64 + j * 16 + fr); // C: col=l&15
                const float s = fmaf(-2.0f, acc[i][j][r], w2v[j]);
                if (s < best) { best = s; bidx = n; }
            }
            #pragma unroll
            for (int m = 1; m <= 8; m <<= 1) { // reduce across 16 fr-lanes
                float    ov = __shfl_xor(best, m);
                unsigned oi = (unsigned)__shfl_xor((int)bidx, m);
                if (ov < best || (ov == best && oi < bidx)) { best = ov; bidx = oi; }
            }
            if (fr == 0) atomicMin(&packed[row], packKey(best, bidx));
        }
    }
}

// ---------------- fallback path (round-2 kernel, proven) ----------------

__device__ __forceinline__ unsigned packhi2(float a, float b) {
    return (__float_as_uint(a) >> 16) | (__float_as_uint(b) & 0xFFFF0000u);
}
__device__ __forceinline__ unsigned packlo2(float a, float b) {
    float ah = __uint_as_float(__float_as_uint(a) & 0xFFFF0000u);
    float bh = __uint_as_float(__float_as_uint(b) & 0xFFFF0000u);
    return (__float_as_uint(a - ah) >> 16) | (__float_as_uint(b - bh) & 0xFFFF0000u);
}
__device__ __forceinline__ uint4 mku4(unsigned a, unsigned b, unsigned c, unsigned d) {
    uint4 r; r.x = a; r.y = b; r.z = c; r.w = d; return r;
}
__device__ __forceinline__ uint4 hi8(float4 p, float4 q) {
    return mku4(packhi2(p.x, p.y), packhi2(p.z, p.w), packhi2(q.x, q.y), packhi2(q.z, q.w));
}
__device__ __forceinline__ uint4 lo8(float4 p, float4 q) {
    return mku4(packlo2(p.x, p.y), packlo2(p.z, p.w), packlo2(q.x, q.y), packlo2(q.z, q.w));
}
__device__ __forceinline__ int lb(int row, int slot) {
    return row * 64 + ((slot ^ ((row >> 1) & 3)) << 4);
}

__global__ __launch_bounds__(256, 2) void som_mfma(const float* __restrict__ X,
                                                   const float* __restrict__ W,
                                                   const float* __restrict__ w2,
                                                   unsigned long long* __restrict__ packed) {
    __shared__ char lds[4 * 8192];
    char* Ahp = lds;
    char* Alp = lds + 8192;
    char* Bhp = lds + 16384;
    char* Blp = lds + 24576;

    const int t     = threadIdx.x;
    const int lane  = t & 63;
    const int wv    = t >> 6;
    const int wr    = wv >> 1, wc = wv & 1;
    const int fr    = lane & 15;
    const int kslot = lane >> 4;

    const int rb = blockIdx.x >> 7;
    const int cb = blockIdx.x & 127;
    const int r0 = rb * 128, c0 = cb * 128;

    const int sr = t >> 1;
    const int sh = t & 1;
    const float* xg = (const float*)X + (size_t)(r0 + sr) * V_DIM + sh * 16;
    const float* wg = (const float*)W + (size_t)(c0 + sr) * V_DIM + sh * 16;

    float4 pa[4], pb[4];
    #pragma unroll
    for (int q = 0; q < 4; ++q) { pa[q] = ((const float4*)xg)[q]; pb[q] = ((const float4*)wg)[q]; }

    f32x4 acc[4][4];
    #pragma unroll
    for (int i = 0; i < 4; ++i)
        #pragma unroll
        for (int j = 0; j < 4; ++j) acc[i][j] = (f32x4){0.f, 0.f, 0.f, 0.f};

    for (int ks = 0; ks < 8; ++ks) {
        uint4 cah0 = hi8(pa[0], pa[1]), cah1 = hi8(pa[2], pa[3]);
        uint4 cal0 = lo8(pa[0], pa[1]), cal1 = lo8(pa[2], pa[3]);
        uint4 cbh0 = hi8(pb[0], pb[1]), cbh1 = hi8(pb[2], pb[3]);
        uint4 cbl0 = lo8(pb[0], pb[1]), cbl1 = lo8(pb[2], pb[3]);

        __syncthreads();
        *(uint4*)(Ahp + lb(sr, 2 * sh))     = cah0;
        *(uint4*)(Ahp + lb(sr, 2 * sh + 1)) = cah1;
        *(uint4*)(Alp + lb(sr, 2 * sh))     = cal0;
        *(uint4*)(Alp + lb(sr, 2 * sh + 1)) = cal1;
        *(uint4*)(Bhp + lb(sr, 2 * sh))     = cbh0;
        *(uint4*)(Bhp + lb(sr, 2 * sh + 1)) = cbh1;
        *(uint4*)(Blp + lb(sr, 2 * sh))     = cbl0;
        *(uint4*)(Blp + lb(sr, 2 * sh + 1)) = cbl1;
        __syncthreads();

        if (ks + 1 < 8) {
            const float* xn = xg + (ks + 1) * 32;
            const float* wn = wg + (ks + 1) * 32;
            #pragma unroll
            for (int q = 0; q < 4; ++q) { pa[q] = ((const float4*)xn)[q]; pb[q] = ((const float4*)wn)[q]; }
        }

        short8 fah[4], fal[4], fbh[4], fbl[4];
        #pragma unroll
        for (int i = 0; i < 4; ++i) {
            int row = wr * 64 + i * 16 + fr;
            fah[i] = *(const short8*)(Ahp + lb(row, kslot));
            fal[i] = *(const short8*)(Alp + lb(row, kslot));
        }
        #pragma unroll
        for (int j = 0; j < 4; ++j) {
            int col = wc * 64 + j * 16 + fr;
            fbh[j] = *(const short8*)(Bhp + lb(col, kslot));
            fbl[j] = *(const short8*)(Blp + lb(col, kslot));
        }
        #pragma unroll
        for (int i = 0; i < 4; ++i)
            #pragma unroll
            for (int j = 0; j < 4; ++j) {
                acc[i][j] = __builtin_amdgcn_mfma_f32_16x16x32_bf16(fah[i], fbh[j], acc[i][j], 0, 0, 0);
                acc[i][j] = __builtin_amdgcn_mfma_f32_16x16x32_bf16(fah[i], fbl[j], acc[i][j], 0, 0, 0);
                acc[i][j] = __builtin_amdgcn_mfma_f32_16x16x32_bf16(fal[i], fbh[j], acc[i][j], 0, 0, 0);
            }
    }

    float w2v[4];
    #pragma unroll
    for (int j = 0; j < 4; ++j) w2v[j] = w2[c0 + wc * 64 + j * 16 + fr];

    #pragma unroll
    for (int i = 0; i < 4; ++i) {
        #pragma unroll
        for (int r = 0; r < 4; ++r) {
            const int row = r0 + wr * 64 + i * 16 + kslot * 4 + r;
            float best = 3.4e38f;
            unsigned bidx = 0u;
            #pragma unroll
            for (int j = 0; j < 4; ++j) {
                const unsigned n = (unsigned)(c0 + wc * 64 + j * 16 + fr);
                const float s = fmaf(-2.0f, acc[i][j][r], w2v[j]);
                if (s < best) { best = s; bidx = n; }
            }
            #pragma unroll
            for (int m = 1; m <= 8; m <<= 1) {
                float    ov = __shfl_xor(best, m);
                unsigned oi = (unsigned)__shfl_xor((int)bidx, m);
                if (ov < best || (ov == best && oi < bidx)) { best = ov; bidx = oi; }
            }
            if (fr == 0) atomicMin(&packed[row], packKey(best, bidx));
        }
    }
}

__global__ __launch_bounds__(256) void finalize(const float* __restrict__ X,
                                                const float* __restrict__ loc,
                                                const unsigned long long* __restrict__ packed,
                                                float* __restrict__ out) {
    int lane = threadIdx.x & 63;
    int wv   = threadIdx.x >> 6;
    int b    = blockIdx.x * 4 + wv;
    float4 v = ((const float4*)(X + (size_t)b * V_DIM))[lane];
    float x2 = v.x * v.x + v.y * v.y + v.z * v.z + v.w * v.w;
    #pragma unroll
    for (int m = 32; m >= 1; m >>= 1) x2 += __shfl_xor(x2, m);
    if (lane == 0) {
        unsigned long long p = packed[b];
        unsigned key = (unsigned)(p >> 32);
        unsigned idx = (unsigned)(p & 0xFFFFFFFFu);
        unsigned sb  = (key & 0x80000000u) ? (key & 0x7FFFFFFFu) : ~key;
        float s  = __uint_as_float(sb);
        float d2 = fmaxf(x2 + s, 0.0f);
        out[2 * b]     = loc[2 * idx];
        out[2 * b + 1] = loc[2 * idx + 1];
        out[2 * B_DIM + b] = sqrtf(d2);
    }
}

extern "C" void kernel_launch(void* const* d_in, const int* in_sizes, int n_in,
                              void* d_out, int out_size, void* d_ws, size_t ws_size,
                              hipStream_t stream) {
    const float* X = (const float*)d_in[0];   // [8192,256]
    const float* W = (const float*)d_in[1];   // [16384,256]
    const float* L = (const float*)d_in[2];   // [16384,2]
    float* out = (float*)d_out;

    float* w2 = (float*)((char*)d_ws + WS_W2_OFF);
    unsigned long long* packed = (unsigned long long*)((char*)d_ws + WS_PACKED_OFF);

    hipMemsetAsync(packed, 0xFF, B_DIM * sizeof(unsigned long long), stream);
    w2_kernel<<<N_DIM / 4, 256, 0, stream>>>(W, w2);

    if (ws_size >= (size_t)WS_FAST_NEED) {
        unsigned short* Xfh = (unsigned short*)((char*)d_ws + WS_PLANES_OFF);
        unsigned short* Xfl = (unsigned short*)((char*)Xfh + XPLANE_BYTES);
        unsigned short* Wfh = (unsigned short*)((char*)Xfl + XPLANE_BYTES);
        unsigned short* Wfl = (unsigned short*)((char*)Wfh + WPLANE_BYTES);
        convert_planes<<<3072, 256, 0, stream>>>(X, W, Xfh, Xfl, Wfh, Wfl);
        som_fast<<<(B_DIM / 128) * (N_DIM / 128), 256, 0, stream>>>(Xfh, Xfl, Wfh, Wfl, w2, packed);
    } else {
        som_mfma<<<(B_DIM / 128) * (N_DIM / 128), 256, 0, stream>>>(X, W, w2, packed);
    }
    finalize<<<B_DIM / 4, 256, 0, stream>>>(X, L, packed, out);
}